// Round 7
// baseline (1078.279 us; speedup 1.0000x reference)
//
#include <hip/hip_runtime.h>
#include <stdint.h>

#define K_DIM 4096
#define N_DIM 11008
#define M_DIM 8192
#define BM 256
#define BN 128
#define BK 64
#define NSLAB (K_DIM / BK)   // 64
#define NBN (N_DIM / BN)     // 86
#define NBM (M_DIM / BM)     // 32
#define NWG (NBN * NBM)      // 2752, % 8 == 0
#define ABUF (BM * BK)       // 16384 halves = 32 KiB per A buffer

// fallback (round-0 validated) kernel params
#define FBM 128
#define FBK 32
#define FASTRIDE 32
#define FBSTRIDE 40

typedef _Float16 half8   __attribute__((ext_vector_type(8)));
typedef _Float16 half2v  __attribute__((ext_vector_type(2)));
typedef float    floatx4 __attribute__((ext_vector_type(4)));

#define WS_NEEDED ((size_t)M_DIM * K_DIM * 2)   // 64 MiB: fp16 copy of x

__device__ __forceinline__ void async_lds16(const void* g, void* l) {
    __builtin_amdgcn_global_load_lds(
        (const __attribute__((address_space(1))) uint32_t*)g,
        (__attribute__((address_space(3))) uint32_t*)l, 16, 0, 0);
}

// ---------------- prepass: x fp32 -> fp16 (lossless; values are fp16-representable) ----
__global__ __launch_bounds__(256) void cvt_a(const float* __restrict__ x,
                                             _Float16* __restrict__ xh) {
    const size_t i = ((size_t)blockIdx.x * 256 + threadIdx.x) * 8;
    const float4 a = *(const float4*)(x + i);
    const float4 b = *(const float4*)(x + i + 4);
    half8 h;
    h[0] = (_Float16)a.x; h[1] = (_Float16)a.y; h[2] = (_Float16)a.z; h[3] = (_Float16)a.w;
    h[4] = (_Float16)b.x; h[5] = (_Float16)b.y; h[6] = (_Float16)b.z; h[7] = (_Float16)b.w;
    *(half8*)(xh + i) = h;
}

// ---------------- main GEMM: r6 pipeline, 4 waves of 128x64 (LDS reads -25%) ----------
// LDS-read-bound fix: FLOP/LDS-byte = wm*wn/(wm+wn); 128x64 wave tile = 42.7 vs 64x64's
// 32. Block 256x128 stays, 256 threads, acc 128 VGPR (launch_bounds(256,2) caps at 256),
// LDS 80 KiB -> 2 blocks/CU (8 waves). Pipeline identical to r6: A dbuf + counted vmcnt
// (DMA(t+1)=8 + pv prefetch=3 stay in flight), zero-conflict XOR chunk swizzle both sides.
__global__ __launch_bounds__(256, 2) void ternary_gemm_w2(
    const _Float16* __restrict__ xh,   // (M, K) fp16
    const int*   __restrict__ pw,      // (K/16, N) packed 2-bit codes
    const float* __restrict__ scales,  // (K/128, N) fp32 holding fp16 values
    const float* __restrict__ bias,    // (N,) fp32 holding fp16 values
    float*       __restrict__ out)     // (M, N) fp32
{
    __shared__ __align__(16) _Float16 lds_a[2 * ABUF];  // 64 KiB, linear dest (DMA)
    __shared__ __align__(16) _Float16 lds_b[BN * BK];   // 16 KiB, XOR-swizzled content

    const int tid  = threadIdx.x;
    const int lane = tid & 63;
    const int w    = tid >> 6;          // 0..3

    // XCD-aware bijective swizzle; m-panel-major within an XCD chunk (FETCH 456->276MB)
    const int bid = blockIdx.x;
    const int swz = (bid & 7) * (NWG / 8) + (bid >> 3);
    const int m0 = (swz / NBN) * BM;
    const int n0 = (swz % NBN) * BN;

    const int band = (w >> 1) * 128;    // 4 waves = 2m x 2n; wave tile 128x64
    const int wn   = (w & 1) * 64;

    // ---- A staging: 8 x 16B DMA per thread; linear LDS dest, pre-swizzled source ----
    // LDS slot (row, c) holds global chunk c ^ (row & 7)  (r6's zero-conflict pattern).
    const int arow0 = tid >> 3;                        // 0..31 (i adds 32)
    const int achk  = (tid & 7) ^ (arow0 & 7);         // i*32 == 0 mod 8
    const _Float16* gaBase = xh + (size_t)(m0 + arow0) * K_DIM + achk * 8;
    const int laBase = tid * 8;                        // halves; i adds 2048

    // ---- B staging: thread = (col nb, dword-pair kp); 2 dwords -> 4 swizzled chunks ----
    const int nb = tid >> 1;                           // 0..127
    const int kp = tid & 1;                            // dword pair {2kp, 2kp+1}
    const int* pwp = pw + (size_t)(kp * 2) * N_DIM + n0 + nb;
    const float* scp = scales + n0 + nb;
    const int s7  = nb & 7;
    const int c0a = (kp * 4 + 0) ^ s7;                 // chunk slots (dword kp*2)
    const int c0b = (kp * 4 + 1) ^ s7;
    const int c1a = (kp * 4 + 2) ^ s7;                 // (dword kp*2+1)
    const int c1b = (kp * 4 + 3) ^ s7;
    _Float16* bl = lds_b + nb * BK;

    floatx4 acc[8][4];
    #pragma unroll
    for (int i = 0; i < 8; ++i)
        #pragma unroll
        for (int j = 0; j < 4; ++j)
            acc[i][j] = floatx4{0.f, 0.f, 0.f, 0.f};

    const int lr = lane & 15;                          // row (A) / col (B,C) in 16-tile
    const int g  = lane >> 4;                          // k-quad
    const int x7 = lr & 7;

    auto stage_a = [&](int t, int buf) {
        #pragma unroll
        for (int i = 0; i < 8; ++i)
            async_lds16(gaBase + (size_t)i * 32 * K_DIM + t * BK,
                        lds_a + buf * ABUF + laBase + i * 2048);
    };
    // exact ternary dequant: 16 codes -> fp16 {-s, 0, +s} via v_perm byte templates
    auto permq = [](uint32_t v, uint32_t tmpl, uint32_t* q) {
        #pragma unroll
        for (int j = 0; j < 8; ++j) {
            uint32_t t4 = (v >> (4 * j)) & 0xFu;             // c0 @bits1:0, c1 @bits3:2
            uint32_t sp = (t4 | (t4 << 14)) & 0x00030003u;   // c0 @byte0, c1 @byte2
            uint32_t sel = ((sp & 0x00010001u) << 1) | ((0x00030003u - sp) << 8);
            q[j] = __builtin_amdgcn_perm(tmpl, tmpl, sel);
        }
    };
    auto stage_b = [&](uint32_t v0, uint32_t v1, float scf) {
        _Float16 sh = (_Float16)scf;                   // lossless (value is fp16)
        uint32_t sbits = (uint32_t)__builtin_bit_cast(unsigned short, sh);
        // template bytes: [0]=lo(s) [1]=hi(+s) [2]=0x00 [3]=hi(-s); s > 0
        uint32_t tmpl = sbits | (((sbits >> 8) ^ 0x80u) << 24);
        uint32_t q[8];
        permq(v0, tmpl, q);
        *(uint4*)(bl + c0a * 8) = make_uint4(q[0], q[1], q[2], q[3]);
        *(uint4*)(bl + c0b * 8) = make_uint4(q[4], q[5], q[6], q[7]);
        permq(v1, tmpl, q);
        *(uint4*)(bl + c1a * 8) = make_uint4(q[0], q[1], q[2], q[3]);
        *(uint4*)(bl + c1b * 8) = make_uint4(q[4], q[5], q[6], q[7]);
    };

    // ---- prologue: DMA slab 0 into buf0; pv(0), pv(1) loaded ----
    stage_a(0, 0);
    uint32_t pv0a = (uint32_t)pwp[0];
    uint32_t pv0b = (uint32_t)pwp[(size_t)1 * N_DIM];
    float    sv0  = scp[0];
    uint32_t pv1a = (uint32_t)pwp[(size_t)4 * N_DIM];
    uint32_t pv1b = (uint32_t)pwp[(size_t)5 * N_DIM];
    float    sv1  = scp[0];                            // group of slab 1 == 0

    int aoff[8], boff[4];
    #pragma unroll
    for (int t = 0; t < 8; ++t) aoff[t] = (band + t * 16 + lr) * BK;
    #pragma unroll
    for (int t = 0; t < 4; ++t) boff[t] = (wn + t * 16 + lr) * BK;

    for (int t = 0; t < NSLAB; ++t) {
        const int cur = t & 1;

        // (a) issue next slab's A-DMA into the other buffer (in flight through MFMA(t))
        if (t + 1 < NSLAB) stage_a(t + 1, cur ^ 1);
        // (b) prefetch slab t+2's packed dwords + scale
        uint32_t pv2a = 0, pv2b = 0; float sv2 = 0.f;
        if (t + 2 < NSLAB) {
            pv2a = (uint32_t)pwp[(size_t)((t + 2) * 4 + 0) * N_DIM];
            pv2b = (uint32_t)pwp[(size_t)((t + 2) * 4 + 1) * N_DIM];
            sv2  = scp[(size_t)((t + 2) >> 1) * N_DIM];
        }
        // (c) B(t): dequant + swizzled ds_write (lds_b free since barrier (g) of t-1)
        stage_b(pv0a, pv0b, sv0);

        // (d) drain DMA(t) only; DMA(t+1) [8] + pv2/sv2 [3] remain outstanding (T4)
        if (t + 2 < NSLAB)      asm volatile("s_waitcnt vmcnt(11)" ::: "memory");
        else if (t + 1 < NSLAB) asm volatile("s_waitcnt vmcnt(8)"  ::: "memory");
        else                    asm volatile("s_waitcnt vmcnt(0)"  ::: "memory");
        asm volatile("s_waitcnt lgkmcnt(0)" ::: "memory");   // my B writes landed
        __builtin_amdgcn_sched_barrier(0);
        __builtin_amdgcn_s_barrier();            // buf[cur] + lds_b published

        // (f) MFMA on buf[cur] + lds_b  (r6's exact zero-conflict fragment pattern)
        const _Float16* Ab = lds_a + cur * ABUF;
        __builtin_amdgcn_s_setprio(1);
        #pragma unroll
        for (int h = 0; h < 2; ++h) {
            const int co = ((h * 4 + g) ^ x7) * 8;
            half8 af[8], bfr[4];
            #pragma unroll
            for (int tt = 0; tt < 8; ++tt) af[tt]  = *(const half8*)&Ab[aoff[tt] + co];
            #pragma unroll
            for (int tt = 0; tt < 4; ++tt) bfr[tt] = *(const half8*)&lds_b[boff[tt] + co];
            #pragma unroll
            for (int mt = 0; mt < 8; ++mt)
                #pragma unroll
                for (int nt = 0; nt < 4; ++nt)
                    acc[mt][nt] = __builtin_amdgcn_mfma_f32_16x16x32_f16(
                        af[mt], bfr[nt], acc[mt][nt], 0, 0, 0);
        }
        __builtin_amdgcn_s_setprio(0);

        // (g) my ds reads complete -> safe for next iter's B overwrite after barrier
        asm volatile("s_waitcnt lgkmcnt(0)" ::: "memory");
        __builtin_amdgcn_sched_barrier(0);
        __builtin_amdgcn_s_barrier();

        pv0a = pv1a; pv0b = pv1b; sv0 = sv1;
        pv1a = pv2a; pv1b = pv2b; sv1 = sv2;
    }

    // ---- epilogue: fp32 acc + fp32 bias, stored unrounded (validated numerics) ----
    float bv[4];
    #pragma unroll
    for (int nt = 0; nt < 4; ++nt) bv[nt] = bias[n0 + wn + nt * 16 + lr];

    const int rbase = g * 4;          // C layout: row = (lane>>4)*4 + reg
    #pragma unroll
    for (int mt = 0; mt < 8; ++mt) {
        #pragma unroll
        for (int nt = 0; nt < 4; ++nt) {
            const int col = n0 + wn + nt * 16 + lr;
            float* op = out + (size_t)(m0 + band + mt * 16 + rbase) * N_DIM + col;
            floatx4 a = acc[mt][nt];
            #pragma unroll
            for (int r = 0; r < 4; ++r)
                op[(size_t)r * N_DIM] = a[r] + bv[nt];
        }
    }
}

// ---------------- fallback: round-0 validated kernel (used if ws too small) ------------
__global__ __launch_bounds__(256, 2) void ternary_gemm(
    const float* __restrict__ x,
    const int*   __restrict__ pw,
    const float* __restrict__ scales,
    const float* __restrict__ bias,
    float*       __restrict__ out)
{
    __shared__ __align__(16) _Float16 lds_a[FBM * FASTRIDE];
    __shared__ __align__(16) _Float16 lds_b[FBM * FBSTRIDE];

    const int tid  = threadIdx.x;
    const int lane = tid & 63;
    const int wave = tid >> 6;

    const int n0 = blockIdx.x * FBM;
    const int m0 = blockIdx.y * FBM;

    const int wm = (wave & 1) * 64;
    const int wn = (wave >> 1) * 64;

    const int nb  = tid & 127;
    const int kpi = tid >> 7;
    const int*   pwp = pw + (size_t)kpi * N_DIM + n0 + nb;
    const float* scp = scales + n0 + nb;
    _Float16* bl = lds_b + nb * FBSTRIDE + kpi * 16;

    floatx4 acc[4][4];
    #pragma unroll
    for (int i = 0; i < 4; ++i)
        #pragma unroll
        for (int j = 0; j < 4; ++j)
            acc[i][j] = floatx4{0.f, 0.f, 0.f, 0.f};

    const int lr = lane & 15;
    const int qk = (lane >> 4) * 8;

    for (int slab = 0; slab < K_DIM / FBK; ++slab) {
        const int k0 = slab * FBK;

        #pragma unroll
        for (int i = 0; i < 4; ++i) {
            const int idx = tid + i * 256;
            const int row = idx >> 3;
            const int kq  = (idx & 7) * 4;
            float4 v4 = *(const float4*)(x + (size_t)(m0 + row) * K_DIM + k0 + kq);
            half2v h0; h0[0] = (_Float16)v4.x; h0[1] = (_Float16)v4.y;
            half2v h1; h1[0] = (_Float16)v4.z; h1[1] = (_Float16)v4.w;
            *(uint2*)(lds_a + row * FASTRIDE + kq) =
                make_uint2(__builtin_bit_cast(uint32_t, h0),
                           __builtin_bit_cast(uint32_t, h1));
        }

        uint32_t v  = (uint32_t)pwp[(size_t)slab * 2 * N_DIM];
        _Float16 sh = (_Float16)scp[(size_t)(slab >> 2) * N_DIM];
        uint32_t sbits = (uint32_t)__builtin_bit_cast(unsigned short, sh);
        uint32_t tmpl = sbits | (((sbits >> 8) ^ 0x80u) << 24);

        uint32_t q[8];
        #pragma unroll
        for (int j = 0; j < 8; ++j) {
            uint32_t t4 = (v >> (4 * j)) & 0xFu;
            uint32_t sp = (t4 | (t4 << 14)) & 0x00030003u;
            uint32_t sel = ((sp & 0x00010001u) << 1) | ((0x00030003u - sp) << 8);
            q[j] = __builtin_amdgcn_perm(tmpl, tmpl, sel);
        }
        *(uint4*)(bl)     = make_uint4(q[0], q[1], q[2], q[3]);
        *(uint4*)(bl + 8) = make_uint4(q[4], q[5], q[6], q[7]);

        __syncthreads();

        half8 af[4], bfr[4];
        #pragma unroll
        for (int t = 0; t < 4; ++t) {
            af[t]  = *(const half8*)&lds_a[(wm + t * 16 + lr) * FASTRIDE + qk];
            bfr[t] = *(const half8*)&lds_b[(wn + t * 16 + lr) * FBSTRIDE + qk];
        }
        #pragma unroll
        for (int mt = 0; mt < 4; ++mt)
            #pragma unroll
            for (int nt = 0; nt < 4; ++nt)
                acc[mt][nt] = __builtin_amdgcn_mfma_f32_16x16x32_f16(
                    af[mt], bfr[nt], acc[mt][nt], 0, 0, 0);

        __syncthreads();
    }

    float bv[4];
    #pragma unroll
    for (int nt = 0; nt < 4; ++nt) bv[nt] = bias[n0 + wn + nt * 16 + lr];

    const int rbase = (lane >> 4) * 4;
    #pragma unroll
    for (int mt = 0; mt < 4; ++mt) {
        #pragma unroll
        for (int nt = 0; nt < 4; ++nt) {
            const int col = n0 + wn + nt * 16 + lr;
            float* op = out + (size_t)(m0 + wm + mt * 16 + rbase) * N_DIM + col;
            floatx4 a = acc[mt][nt];
            #pragma unroll
            for (int r = 0; r < 4; ++r)
                op[(size_t)r * N_DIM] = a[r] + bv[nt];
        }
    }
}

extern "C" void kernel_launch(void* const* d_in, const int* in_sizes, int n_in,
                              void* d_out, int out_size, void* d_ws, size_t ws_size,
                              hipStream_t stream) {
    const float* x  = (const float*)d_in[0];
    const int*   pw = (const int*)d_in[1];
    const float* sc = (const float*)d_in[2];
    const float* bs = (const float*)d_in[3];
    float* out = (float*)d_out;

    if (d_ws != nullptr && ws_size >= WS_NEEDED) {
        _Float16* xh = (_Float16*)d_ws;
        cvt_a<<<dim3((unsigned)((size_t)M_DIM * K_DIM / (256 * 8))), 256, 0, stream>>>(x, xh);
        ternary_gemm_w2<<<dim3(NWG), 256, 0, stream>>>(xh, pw, sc, bs, out);
    } else {
        ternary_gemm<<<dim3(N_DIM / FBM, M_DIM / FBM), 256, 0, stream>>>(x, pw, sc, bs, out);
    }
}